// Round 1
// baseline (1505.327 us; speedup 1.0000x reference)
//
#include <hip/hip_runtime.h>
#include <math.h>

#define T_IN 64
#define TOS 512          // OSAMP * T_IN
#define NPIX 16384       // 128*128
#define C_SHARP 500.0f
#define LR 0.1f
#define MAX_ITER 10

// ws float layout
#define WS_CDC   0
#define WS_SPLAM 1
#define WS_CNN   2       // 3 floats (2..4)
#define WS_AIF   8       // 512
#define WS_TSH   (8+512)
#define WS_S2    (8+1024)

// ---------------------------------------------------------------- setup -----
// Computes aif_os (centered, upsampled), tsh, s2 = sigmoid(500*tsh), sp_lam.
// jax.image.resize 'linear': sample x = (j+0.5)*in/out - 0.5, triangle kernel,
// edge renormalization == clamp to [0, in-1].
__global__ void k_setup(const float* __restrict__ aif,
                        const float* __restrict__ timev,
                        const float* __restrict__ lam,
                        float* __restrict__ ws) {
    __shared__ float a_s[T_IN], t_s[T_IN];
    int i = threadIdx.x;            // 0..511
    if (i < T_IN) { a_s[i] = aif[i]; t_s[i] = timev[i]; }
    __syncthreads();
    float m5 = 0.2f * (a_s[0] + a_s[1] + a_s[2] + a_s[3] + a_s[4]);
    // t_os at NEG_SHIFT=16: x = (16-3.5)/8 = 1.5625 (interior)
    float t16;
    {
        float x = (16.0f - 3.5f) * 0.125f;
        int i0 = (int)x; float f = x - (float)i0;
        t16 = t_s[i0] * (1.0f - f) + t_s[i0 + 1] * f;
    }
    float x = ((float)i - 3.5f) * 0.125f;
    float ao, to;
    if (x <= 0.0f)                 { ao = a_s[0] - m5;        to = t_s[0]; }
    else if (x >= (float)(T_IN-1)) { ao = a_s[T_IN-1] - m5;   to = t_s[T_IN-1]; }
    else {
        int i0 = (int)x; float f = x - (float)i0;
        ao = (a_s[i0] - m5) * (1.0f - f) + (a_s[i0+1] - m5) * f;
        to = t_s[i0] * (1.0f - f) + t_s[i0+1] * f;
    }
    float tsh = to - t16;
    ws[WS_AIF + i] = ao;
    ws[WS_TSH + i] = tsh;
    ws[WS_S2  + i] = 1.0f / (1.0f + __expf(-C_SHARP * tsh));
    if (i == 0) {
        float xl = lam[0];
        ws[WS_SPLAM] = (xl > 0.0f) ? (xl + log1pf(__expf(-xl)))
                                   : log1pf(__expf(xl));
    }
}

// ------------------------------------------------------- C_dc reduction -----
// One wave per pixel (grid-strided), local accumulate, 1 atomic per wave.
__global__ void k_cdc(const float* __restrict__ ctc, float* __restrict__ ws) {
    int lane = threadIdx.x & 63;
    int gw = blockIdx.x * 4 + (threadIdx.x >> 6);   // 0..1023
    float vsum = 0.0f;
    for (int pix = gw; pix < NPIX; pix += 1024) {
        float c = ctc[pix * T_IN + lane];
        float m5 = 0.2f * (__shfl(c,0)+__shfl(c,1)+__shfl(c,2)+__shfl(c,3)+__shfl(c,4));
        float cc = c - m5;
        float ccp = __shfl_up(cc, 1);
        float dcv = (lane == 0) ? cc : (0.4375f * ccp + 0.5625f * cc);
        vsum += dcv * dcv;
    }
    #pragma unroll
    for (int m = 1; m < 64; m <<= 1) vsum += __shfl_xor(vsum, m);
    if (lane == 0) atomicAdd(&ws[WS_CDC], vsum);
}

// ------------------------------------------------------- C_nn reduction -----
__global__ void k_cnn(const float* __restrict__ eta, float* __restrict__ ws) {
    int ch  = blockIdx.x >> 6;                        // 64 blocks per channel
    int idx = (blockIdx.x & 63) * 256 + threadIdx.x;  // 0..16383
    float e = eta[ch * NPIX + idx];
    float v = e * e;
    #pragma unroll
    for (int m = 1; m < 64; m <<= 1) v += __shfl_xor(v, m);
    __shared__ float red[4];
    int lane = threadIdx.x & 63, w = threadIdx.x >> 6;
    if (lane == 0) red[w] = v;
    __syncthreads();
    if (threadIdx.x == 0) atomicAdd(&ws[WS_CNN + ch], red[0]+red[1]+red[2]+red[3]);
}

// ---------------------------------------------------------------- main ------
// One wave per pixel, 4 waves/block. Field buffer: 528 u-slots (8 zero-margin
// each side), skewed g(s)=s+(s>>3) -> lane stride 9 groups -> conflict-free.
#define NGRP 593   // g(527)=592
__global__ __launch_bounds__(256) void k_main(
        const float* __restrict__ ctc,
        const float* __restrict__ eta_nn,
        const float* __restrict__ ws,
        float* __restrict__ out) {
    __shared__ float4 buf[4][NGRP];
    int lane = threadIdx.x & 63;
    int wid  = threadIdx.x >> 6;
    int pix  = blockIdx.x * 4 + wid;
    float4* B = buf[wid];

    // zero margins: s in [0,8) and [520,528)
    if (lane < 8) {
        B[lane] = make_float4(0.f, 0.f, 0.f, 0.f);               // g(s)=s for s<8
        B[520 + lane + 65] = make_float4(0.f, 0.f, 0.f, 0.f);    // g(520+l)=585+l
    }

    float C_dc = ws[WS_CDC];
    float spl  = ws[WS_SPLAM];
    float Cn0  = ws[WS_CNN+0], Cn1 = ws[WS_CNN+1], Cn2 = ws[WS_CNN+2];
    float rscale = 2.0f / C_dc * 0.125f;

    float tshr[8], s2r[8];
    #pragma unroll
    for (int c = 0; c < 8; ++c) {
        int t = lane + 64 * c;
        tshr[c] = ws[WS_TSH + t];
        s2r[c]  = ws[WS_S2  + t];
    }

    // ctc_dc for this lane (= output sample d = lane)
    float dc;
    {
        float c = ctc[pix * T_IN + lane];
        float m5 = 0.2f * (__shfl(c,0)+__shfl(c,1)+__shfl(c,2)+__shfl(c,3)+__shfl(c,4));
        float cc = c - m5;
        float ccp = __shfl_up(cc, 1);
        dc = (lane == 0) ? cc : (0.4375f * ccp + 0.5625f * cc);
    }

    float A  = eta_nn[0*NPIX + pix];
    float K  = eta_nn[1*NPIX + pix];
    float T0 = eta_nn[2*NPIX + pix];
    const float pA = A, pK = K, pT = T0;   // prior
    const float* aif = ws + WS_AIF;

    for (int it = 0; it < MAX_ITER; ++it) {
        // fields: f0 = s1*s2 (= ir/A), f1 = d(ir)/dk, f2 = d(ir)/dt0
        #pragma unroll
        for (int c = 0; c < 8; ++c) {
            int t = lane + 64 * c;
            float d1 = T0 - tshr[c];
            float s1 = 1.0f / (1.0f + __expf(-K * d1));
            float e  = s1 * (1.0f - s1);
            float b  = s2r[c];
            float com = A * e * b;
            int s = t + 8;
            B[s + (s >> 3)] = make_float4(s1 * b, com * d1, com * K, 0.0f);
        }
        __syncthreads();

        // conv_j[d] = sum_a aif_os[a] * f_j[16+8d-a]; zero-margin + clamp
        float a0 = 0.f, a1 = 0.f, a2 = 0.f;
        int v = 24 + 8 * lane;               // = (16+8d) - a + 8
        #pragma unroll 8
        for (int a = 0; a < TOS; ++a) {
            int s = min(max(v, 0), 527);
            float4 w = B[s + (s >> 3)];
            float av = aif[a];               // wave-uniform -> s_load
            a0 = fmaf(av, w.x, a0);
            a1 = fmaf(av, w.y, a1);
            a2 = fmaf(av, w.z, a2);
            --v;
        }
        __syncthreads();

        float est = A * a0 * 0.125f;
        float rr  = (est - dc) * rscale;     // 2(est-dc)/C_dc * 1/8
        float gA = rr * a0, gK = rr * a1, gT = rr * a2;
        #pragma unroll
        for (int m = 1; m < 64; m <<= 1) {
            gA += __shfl_xor(gA, m);
            gK += __shfl_xor(gK, m);
            gT += __shfl_xor(gT, m);
        }
        gA += 2.0f * spl * (A  - pA) / Cn0 + ((A  < 0.0f) ? 2.0f * A  : 0.0f);
        gK += 2.0f * spl * (K  - pK) / Cn1 + ((K  < 0.0f) ? 2.0f * K  : 0.0f);
        gT += 2.0f * spl * (T0 - pT) / Cn2 + ((T0 < 0.0f) ? 2.0f * T0 : 0.0f);
        A  -= LR * gA;
        K  -= LR * gK;
        T0 -= LR * gT;
    }

    if (lane == 0) {
        out[0*NPIX + pix] = A;
        out[1*NPIX + pix] = K;
        out[2*NPIX + pix] = T0;
    }
}

// -------------------------------------------------------------- launch ------
extern "C" void kernel_launch(void* const* d_in, const int* in_sizes, int n_in,
                              void* d_out, int out_size, void* d_ws, size_t ws_size,
                              hipStream_t stream) {
    const float* ctc   = (const float*)d_in[0];
    const float* aif   = (const float*)d_in[1];
    const float* timev = (const float*)d_in[2];
    // d_in[3] = seg (unused by reference)
    const float* eta   = (const float*)d_in[4];
    const float* lam   = (const float*)d_in[5];
    float* ws  = (float*)d_ws;
    float* out = (float*)d_out;

    hipMemsetAsync(ws, 0, 8 * sizeof(float), stream);   // atomic accumulators
    k_setup<<<1, 512, 0, stream>>>(aif, timev, lam, ws);
    k_cdc<<<256, 256, 0, stream>>>(ctc, ws);
    k_cnn<<<192, 256, 0, stream>>>(eta, ws);
    k_main<<<NPIX / 4, 256, 0, stream>>>(ctc, eta, ws, out);
}

// Round 5
// 209.595 us; speedup vs baseline: 7.1821x; 7.1821x over previous
//
#include <hip/hip_runtime.h>
#include <math.h>

#define T_IN 64
#define NPIX 16384
#define MAX_ITER 10

// ws float layout
#define WS_CDC   0
#define WS_SPLAM 1
#define WS_CNN   2       // 3 floats
#define WS_AIF   8       // 512 floats
#define WS_TSH   520     // 512 floats

typedef _Float16 half8_t __attribute__((ext_vector_type(8)));
typedef __fp16   fp16x2  __attribute__((ext_vector_type(2)));
typedef float    f32x4   __attribute__((ext_vector_type(4)));
typedef int      i32x4   __attribute__((ext_vector_type(4)));

union H8 { half8_t v; fp16x2 h2[4]; i32x4 i4; };

__device__ __forceinline__ float rcp_fast(float x) { return __builtin_amdgcn_rcpf(x); }

// ---------------------------------------------------------------- setup -----
// aif_os (centered, upsampled), tsh = t_os - t_os[16], sp_lam.
// jax.image.resize 'linear': x = (j+0.5)*in/out - 0.5, edge renorm == clamp.
__global__ void k_setup(const float* __restrict__ aif,
                        const float* __restrict__ timev,
                        const float* __restrict__ lam,
                        float* __restrict__ ws) {
    __shared__ float a_s[T_IN], t_s[T_IN];
    int i = threadIdx.x;            // 0..511
    if (i < T_IN) { a_s[i] = aif[i]; t_s[i] = timev[i]; }
    __syncthreads();
    float m5 = 0.2f * (a_s[0] + a_s[1] + a_s[2] + a_s[3] + a_s[4]);
    float t16;
    {
        float x = (16.0f - 3.5f) * 0.125f;
        int i0 = (int)x; float f = x - (float)i0;
        t16 = t_s[i0] * (1.0f - f) + t_s[i0 + 1] * f;
    }
    float x = ((float)i - 3.5f) * 0.125f;
    float ao, to;
    if (x <= 0.0f)                 { ao = a_s[0] - m5;       to = t_s[0]; }
    else if (x >= (float)(T_IN-1)) { ao = a_s[T_IN-1] - m5;  to = t_s[T_IN-1]; }
    else {
        int i0 = (int)x; float f = x - (float)i0;
        ao = (a_s[i0] - m5) * (1.0f - f) + (a_s[i0+1] - m5) * f;
        to = t_s[i0] * (1.0f - f) + t_s[i0+1] * f;
    }
    ws[WS_AIF + i] = ao;
    ws[WS_TSH + i] = to - t16;
    if (i == 0) {
        float xl = lam[0];
        ws[WS_SPLAM] = (xl > 0.0f) ? (xl + log1pf(__expf(-xl)))
                                   : log1pf(__expf(xl));
    }
}

// ------------------------------------------------------- C_dc reduction -----
__global__ void k_cdc(const float* __restrict__ ctc, float* __restrict__ ws) {
    int lane = threadIdx.x & 63;
    int gw = blockIdx.x * 4 + (threadIdx.x >> 6);
    float vsum = 0.0f;
    for (int pix = gw; pix < NPIX; pix += 1024) {
        float c = ctc[pix * T_IN + lane];
        float m5 = 0.2f * (__shfl(c,0)+__shfl(c,1)+__shfl(c,2)+__shfl(c,3)+__shfl(c,4));
        float cc = c - m5;
        float ccp = __shfl_up(cc, 1);
        float dcv = (lane == 0) ? cc : (0.4375f * ccp + 0.5625f * cc);
        vsum += dcv * dcv;
    }
    #pragma unroll
    for (int m = 1; m < 64; m <<= 1) vsum += __shfl_xor(vsum, m);
    if (lane == 0) atomicAdd(&ws[WS_CDC], vsum);
}

// ------------------------------------------------------- C_nn reduction -----
__global__ void k_cnn(const float* __restrict__ eta, float* __restrict__ ws) {
    int ch  = blockIdx.x >> 6;
    int idx = (blockIdx.x & 63) * 256 + threadIdx.x;
    float e = eta[ch * NPIX + idx];
    float v = e * e;
    #pragma unroll
    for (int m = 1; m < 64; m <<= 1) v += __shfl_xor(v, m);
    __shared__ float red[4];
    int lane = threadIdx.x & 63, w = threadIdx.x >> 6;
    if (lane == 0) red[w] = v;
    __syncthreads();
    if (threadIdx.x == 0) atomicAdd(&ws[WS_CNN + ch], red[0]+red[1]+red[2]+red[3]);
}

// ---------------------------------------------------------------- main ------
// MFMA formulation with compensated hi/lo f16 split on BOTH operands:
//   Y = Ah*Bh + Al*Bh + Ah*Bl   (Al*Bl ~ 2^-22, dropped)  -> fp32-level conv.
// Per wave: 16 pixels. Rows = {s1, e*d1, e} per pixel,
// B[t][d] = s2[t]*aif_os[16+8d-t]/8 (43 nonzero 32x16 tiles in LDS, hi+lo).
// A-frags built analytically in registers (A-layout: m=lane&15, k=q*8+j).
// C-layout: row(pixel)=q*4+reg, col(d)=nt*16+n.  [m89/m121-128 layouts]
#define NSLOT 43
__global__ __launch_bounds__(256) void k_main(const float* __restrict__ ctc,
                                              const float* __restrict__ eta,
                                              const float* __restrict__ ws,
                                              float* __restrict__ out) {
    __shared__ i32x4 Bs[NSLOT * 64];   // 43 KB  (hi)
    __shared__ i32x4 Bl[NSLOT * 64];   // 43 KB  (lo)
    __shared__ float tshs[512];        // 2 KB
    const int tid  = threadIdx.x;
    const int lane = tid & 63;
    const int wid  = tid >> 6;
    const int q = lane >> 4, n = lane & 15;

    // FIX(R5): block is 256 threads — each must load TWO tsh elements.
    // R3/R4 left tshs[256..511] uninitialized -> ~2.5e-2 systematic error.
    tshs[tid]       = ws[WS_TSH + tid];
    tshs[tid + 256] = ws[WS_TSH + tid + 256];
    __syncthreads();

    // ---- build B tiles in LDS (one-time), hi + compensation lo ----
    for (int idx = tid; idx < NSLOT * 64; idx += 256) {
        int slot = idx >> 6, l = idx & 63;
        int kt, nt;
        if (slot < 20)      { kt = slot >> 2; nt = slot & 3; }
        else if (slot < 32) { int s = slot - 20; int d3 = s / 3; kt = 5 + d3; nt = 1 + (s - 3*d3); }
        else if (slot < 40) { int s = slot - 32; kt = 9 + (s >> 1); nt = 2 + (s & 1); }
        else                { kt = 13 + (slot - 40); nt = 3; }
        int kbase = 32*kt + 8*(l >> 4);
        int m = 16 + 8 * (16*nt + (l & 15));   // m_d = 16+8d
        H8 bh, bl;
        #pragma unroll
        for (int jj = 0; jj < 4; ++jj) {
            float v[2];
            #pragma unroll
            for (int h = 0; h < 2; ++h) {
                int k  = kbase + 2*jj + h;
                int ai = m - k;
                float s2 = 1.0f / (1.0f + __expf(-500.0f * tshs[k]));
                v[h] = (ai >= 0 && ai < 512) ? s2 * ws[WS_AIF + ai] * 0.125f : 0.0f;
            }
            fp16x2 hh = __builtin_amdgcn_cvt_pkrtz(v[0], v[1]);
            bh.h2[jj] = hh;
            bl.h2[jj] = __builtin_amdgcn_cvt_pkrtz(v[0] - (float)hh[0],
                                                   v[1] - (float)hh[1]);
        }
        Bs[idx] = bh.i4;
        Bl[idx] = bl.i4;
    }
    __syncthreads();

    const int pixbase = blockIdx.x * 64 + wid * 16;
    const int mypix   = pixbase + n;

    float A  = eta[mypix];
    float K  = eta[NPIX + mypix];
    float T0 = eta[2*NPIX + mypix];
    const float pA = A, pK = K, pT = T0;

    // ctc_dc in C-layout registers: dcreg[nt][reg] = dc[p=q*4+reg][d=nt*16+n]
    float dcreg[4][4];
    #pragma unroll
    for (int reg = 0; reg < 4; ++reg) {
        const float* cp = ctc + (pixbase + q*4 + reg) * T_IN;
        float m5 = 0.2f * (cp[0]+cp[1]+cp[2]+cp[3]+cp[4]);
        #pragma unroll
        for (int nt = 0; nt < 4; ++nt) {
            int d = nt*16 + n;
            float cc = cp[d] - m5;
            float cm = cp[(d > 0) ? d-1 : 0] - m5;
            dcreg[nt][reg] = (d == 0) ? cc : (0.4375f*cm + 0.5625f*cc);
        }
    }

    const float C_dc = ws[WS_CDC];
    const float spl  = ws[WS_SPLAM];
    const float cdc2 = 2.0f / C_dc;
    const float rgA  = 2.0f * spl / ws[WS_CNN+0];
    const float rgK  = 2.0f * spl / ws[WS_CNN+1];
    const float rgT  = 2.0f * spl / ws[WS_CNN+2];

    const int NTMIN[16] = {0,0,0,0,0,1,1,1,1,2,2,2,2,3,3,3};
    const int TOFS[16]  = {0,4,8,12,16,20,23,26,29,32,34,36,38,40,41,42};

    #pragma unroll 1
    for (int it = 0; it < MAX_ITER; ++it) {
        f32x4 acc[3][4];
        #pragma unroll
        for (int f = 0; f < 3; ++f)
            #pragma unroll
            for (int t = 0; t < 4; ++t)
                acc[f][t] = (f32x4){0.f, 0.f, 0.f, 0.f};

        float nK = -K;
        #pragma unroll
        for (int kt = 0; kt < 16; ++kt) {
            f32x4 tv0 = *(const f32x4*)&tshs[32*kt + 8*q];
            f32x4 tv1 = *(const f32x4*)&tshs[32*kt + 8*q + 4];
            float ts[8];
            ts[0]=tv0[0]; ts[1]=tv0[1]; ts[2]=tv0[2]; ts[3]=tv0[3];
            ts[4]=tv1[0]; ts[5]=tv1[1]; ts[6]=tv1[2]; ts[7]=tv1[3];
            H8 F0h, F1h, F2h, F0l, F1l, F2l;
            #pragma unroll
            for (int jj = 0; jj < 4; ++jj) {
                float d1a = T0 - ts[2*jj], d1b = T0 - ts[2*jj+1];
                float xa = __expf(nK * d1a), xb = __expf(nK * d1b);
                float s1a = rcp_fast(1.0f + xa), s1b = rcp_fast(1.0f + xb);
                float ea = fmaf(-s1a, s1a, s1a), eb = fmaf(-s1b, s1b, s1b);
                float p1a = ea * d1a, p1b = eb * d1b;
                fp16x2 h0 = __builtin_amdgcn_cvt_pkrtz(s1a, s1b);
                fp16x2 h1 = __builtin_amdgcn_cvt_pkrtz(p1a, p1b);
                fp16x2 h2 = __builtin_amdgcn_cvt_pkrtz(ea, eb);
                F0h.h2[jj] = h0;
                F1h.h2[jj] = h1;
                F2h.h2[jj] = h2;
                F0l.h2[jj] = __builtin_amdgcn_cvt_pkrtz(s1a - (float)h0[0], s1b - (float)h0[1]);
                F1l.h2[jj] = __builtin_amdgcn_cvt_pkrtz(p1a - (float)h1[0], p1b - (float)h1[1]);
                F2l.h2[jj] = __builtin_amdgcn_cvt_pkrtz(ea  - (float)h2[0], eb  - (float)h2[1]);
            }
            #pragma unroll
            for (int nt = NTMIN[kt]; nt < 4; ++nt) {
                int slot = TOFS[kt] + nt - NTMIN[kt];
                H8 bh; bh.i4 = Bs[slot*64 + lane];
                H8 bl; bl.i4 = Bl[slot*64 + lane];
                acc[0][nt] = __builtin_amdgcn_mfma_f32_16x16x32_f16(F0h.v, bh.v, acc[0][nt], 0, 0, 0);
                acc[1][nt] = __builtin_amdgcn_mfma_f32_16x16x32_f16(F1h.v, bh.v, acc[1][nt], 0, 0, 0);
                acc[2][nt] = __builtin_amdgcn_mfma_f32_16x16x32_f16(F2h.v, bh.v, acc[2][nt], 0, 0, 0);
                acc[0][nt] = __builtin_amdgcn_mfma_f32_16x16x32_f16(F0l.v, bh.v, acc[0][nt], 0, 0, 0);
                acc[1][nt] = __builtin_amdgcn_mfma_f32_16x16x32_f16(F1l.v, bh.v, acc[1][nt], 0, 0, 0);
                acc[2][nt] = __builtin_amdgcn_mfma_f32_16x16x32_f16(F2l.v, bh.v, acc[2][nt], 0, 0, 0);
                acc[0][nt] = __builtin_amdgcn_mfma_f32_16x16x32_f16(F0h.v, bl.v, acc[0][nt], 0, 0, 0);
                acc[1][nt] = __builtin_amdgcn_mfma_f32_16x16x32_f16(F1h.v, bl.v, acc[1][nt], 0, 0, 0);
                acc[2][nt] = __builtin_amdgcn_mfma_f32_16x16x32_f16(F2h.v, bl.v, acc[2][nt], 0, 0, 0);
            }
        }

        // ---- epilogue: residuals, per-pixel gradient dots, reduce, route ----
        float Ap[4];
        #pragma unroll
        for (int r = 0; r < 4; ++r) Ap[r] = __shfl(A, q*4 + r);

        float SA[4], SK[4], ST[4];
        #pragma unroll
        for (int r = 0; r < 4; ++r) { SA[r] = 0.f; SK[r] = 0.f; ST[r] = 0.f; }
        #pragma unroll
        for (int nt = 0; nt < 4; ++nt)
            #pragma unroll
            for (int r = 0; r < 4; ++r) {
                float Y0 = acc[0][nt][r], Y1 = acc[1][nt][r], Y2 = acc[2][nt][r];
                float rr = fmaf(Ap[r], Y0, -dcreg[nt][r]);   // est - dc
                SA[r] = fmaf(rr, Y0, SA[r]);
                SK[r] = fmaf(rr, Y1, SK[r]);
                ST[r] = fmaf(rr, Y2, ST[r]);
            }
        #pragma unroll
        for (int r = 0; r < 4; ++r)
            #pragma unroll
            for (int m = 1; m < 16; m <<= 1) {
                SA[r] += __shfl_xor(SA[r], m);
                SK[r] += __shfl_xor(SK[r], m);
                ST[r] += __shfl_xor(ST[r], m);
            }
        // route: pixel p=n lives in group p>>2, slot p&3
        int src = (n >> 2) * 16;
        float GA = 0.f, GK = 0.f, GT = 0.f;
        #pragma unroll
        for (int r = 0; r < 4; ++r) {
            float tA = __shfl(SA[r], src);
            float tK = __shfl(SK[r], src);
            float tT = __shfl(ST[r], src);
            if ((n & 3) == r) { GA = tA; GK = tK; GT = tT; }
        }

        float gA = fmaf(rgA, A  - pA, cdc2 * GA)         + 2.0f * fminf(A,  0.f);
        float gK = fmaf(rgK, K  - pK, cdc2 * A * GK)     + 2.0f * fminf(K,  0.f);
        float gT = fmaf(rgT, T0 - pT, cdc2 * A * K * GT) + 2.0f * fminf(T0, 0.f);
        A  -= 0.1f * gA;
        K  -= 0.1f * gK;
        T0 -= 0.1f * gT;
    }

    if (lane < 16) {
        out[mypix]          = A;
        out[NPIX + mypix]   = K;
        out[2*NPIX + mypix] = T0;
    }
}

// -------------------------------------------------------------- launch ------
extern "C" void kernel_launch(void* const* d_in, const int* in_sizes, int n_in,
                              void* d_out, int out_size, void* d_ws, size_t ws_size,
                              hipStream_t stream) {
    const float* ctc   = (const float*)d_in[0];
    const float* aif   = (const float*)d_in[1];
    const float* timev = (const float*)d_in[2];
    const float* eta   = (const float*)d_in[4];
    const float* lam   = (const float*)d_in[5];
    float* ws  = (float*)d_ws;
    float* out = (float*)d_out;

    (void)hipMemsetAsync(ws, 0, 8 * sizeof(float), stream);
    k_setup<<<1, 512, 0, stream>>>(aif, timev, lam, ws);
    k_cdc<<<256, 256, 0, stream>>>(ctc, ws);
    k_cnn<<<192, 256, 0, stream>>>(eta, ws);
    k_main<<<NPIX / 64, 256, 0, stream>>>(ctc, eta, ws, out);
}

// Round 7
// 131.687 us; speedup vs baseline: 11.4311x; 1.5916x over previous
//
#include <hip/hip_runtime.h>
#include <math.h>

#define T_IN 64
#define NPIX 16384
#define MAX_ITER 10

// ws float layout
#define WS_CDC   0
#define WS_SPLAM 1
#define WS_CNN   2       // 3 floats
#define WS_AIF   8       // 512 floats
#define WS_TSH   520     // 512 floats

typedef _Float16 half8_t __attribute__((ext_vector_type(8)));
typedef __fp16   fp16x2  __attribute__((ext_vector_type(2)));
typedef float    f32x4   __attribute__((ext_vector_type(4)));
typedef int      i32x4   __attribute__((ext_vector_type(4)));

union H8 { half8_t v; fp16x2 h2[4]; i32x4 i4; };

__device__ __forceinline__ float rcp_fast(float x) { return __builtin_amdgcn_rcpf(x); }

// ---------------------------------------------------------------- prep ------
// Fused: block 0 = setup (aif_os, tsh, sp_lam); blocks 1..1024 = C_dc
// (1024*256 threads * float4 = 1,048,576 floats = full ctc);
// blocks 1025..1072 = C_nn.  A pixel row (64 floats) spans 16 float4-threads.
__global__ __launch_bounds__(256) void k_prep(const float* __restrict__ aif,
        const float* __restrict__ timev, const float* __restrict__ lam,
        const float* __restrict__ ctc, const float* __restrict__ eta,
        float* __restrict__ ws) {
    const int b = blockIdx.x, tid = threadIdx.x;
    __shared__ float a_s[64], t_s[64];
    __shared__ float red[4];
    if (b == 0) {
        if (tid < 64) { a_s[tid] = aif[tid]; t_s[tid] = timev[tid]; }
        __syncthreads();
        float m5 = 0.2f * (a_s[0]+a_s[1]+a_s[2]+a_s[3]+a_s[4]);
        float t16;
        {   // t_os[16]: x = (16-3.5)/8 = 1.5625
            float xx = 1.5625f; int i0 = (int)xx; float f = xx - (float)i0;
            t16 = t_s[i0]*(1.0f-f) + t_s[i0+1]*f;
        }
        #pragma unroll
        for (int rep = 0; rep < 2; ++rep) {
            int i = tid + 256*rep;
            float x = ((float)i - 3.5f) * 0.125f;
            float ao, to;
            if (x <= 0.0f)       { ao = a_s[0]  - m5; to = t_s[0];  }
            else if (x >= 63.0f) { ao = a_s[63] - m5; to = t_s[63]; }
            else {
                int i0 = (int)x; float f = x - (float)i0;
                ao = (a_s[i0]-m5)*(1.0f-f) + (a_s[i0+1]-m5)*f;
                to = t_s[i0]*(1.0f-f) + t_s[i0+1]*f;
            }
            ws[WS_AIF + i] = ao;
            ws[WS_TSH + i] = to - t16;
        }
        if (tid == 0) {
            float xl = lam[0];
            ws[WS_SPLAM] = (xl > 0.0f) ? (xl + log1pf(__expf(-xl)))
                                       : log1pf(__expf(xl));
        }
    } else if (b <= 1024) {
        // ---- C_dc: pixel row = 16 consecutive float4 threads ----
        int idx  = (b-1)*256 + tid;          // 0..262143 float4
        int lane = tid & 63;
        f32x4 v = ((const f32x4*)ctc)[idx];
        int c16  = idx & 15;                 // position within pixel row
        int base = lane & ~15;               // pixel's first lane (4 px/wave)
        float sum4 = v.x+v.y+v.z+v.w;
        float m5 = 0.2f * (__shfl(sum4, base) + __shfl(v.x, base+1));
        float cm1 = __shfl_up(v.w, 1);
        float c0=v.x-m5, c1=v.y-m5, c2=v.z-m5, c3=v.w-m5;
        float cm = cm1 - m5;
        float d0 = (c16 == 0) ? c0 : fmaf(0.4375f, cm, 0.5625f*c0);
        float d1 = fmaf(0.4375f, c0, 0.5625f*c1);
        float d2 = fmaf(0.4375f, c1, 0.5625f*c2);
        float d3 = fmaf(0.4375f, c2, 0.5625f*c3);
        float vs = d0*d0 + d1*d1 + d2*d2 + d3*d3;
        #pragma unroll
        for (int m = 1; m < 64; m <<= 1) vs += __shfl_xor(vs, m);
        if (lane == 0) red[tid >> 6] = vs;
        __syncthreads();
        if (tid == 0) atomicAdd(&ws[WS_CDC], red[0]+red[1]+red[2]+red[3]);
    } else {
        // ---- C_nn: 48 blocks, 16 blocks per channel (4096 f32x4/channel) ----
        int idx  = (b-1025)*256 + tid;       // 0..12287 float4
        int lane = tid & 63;
        f32x4 v = ((const f32x4*)eta)[idx];
        int ch = idx >> 12;
        float vs = v.x*v.x + v.y*v.y + v.z*v.z + v.w*v.w;
        #pragma unroll
        for (int m = 1; m < 64; m <<= 1) vs += __shfl_xor(vs, m);
        if (lane == 0) red[tid >> 6] = vs;
        __syncthreads();
        if (tid == 0) atomicAdd(&ws[WS_CNN + ch], red[0]+red[1]+red[2]+red[3]);
    }
}

// ---------------------------------------------------------------- main ------
// MFMA, hi-only f16 with RTN conversions. Per wave: 16 pixels.
// B[t][d] = s2[t]*aif_os[16+8d-t]/8 — built in LDS once, then hoisted to
// 43*4 = 172 VGPRs (iteration-invariant; 1 wave/SIMD so VGPRs are free).
// A-fields {s1, e*d1, e} built via exp-recurrence (tsh arithmetic, step
// 0.125 except 4 flat samples each end -> exact path for kt 0/15 edges).
// C-layout: row(pixel)=q*4+reg, col(d)=nt*16+n.
#define NSLOT 43
__global__ __launch_bounds__(256, 1) void k_main(const float* __restrict__ ctc,
                                                 const float* __restrict__ eta,
                                                 const float* __restrict__ ws,
                                                 float* __restrict__ out) {
    __shared__ i32x4 Bs[NSLOT * 64];   // 43 KB
    __shared__ float tshs[512];        // 2 KB
    const int tid  = threadIdx.x;
    const int lane = tid & 63;
    const int wid  = tid >> 6;
    const int q = lane >> 4, n = lane & 15;

    tshs[tid]       = ws[WS_TSH + tid];
    tshs[tid + 256] = ws[WS_TSH + tid + 256];
    __syncthreads();

    // ---- build B tiles in LDS (one-time), RTN ----
    for (int idx = tid; idx < NSLOT * 64; idx += 256) {
        int slot = idx >> 6, l = idx & 63;
        int kt, nt;
        if (slot < 20)      { kt = slot >> 2; nt = slot & 3; }
        else if (slot < 32) { int s = slot - 20; int d3 = s / 3; kt = 5 + d3; nt = 1 + (s - 3*d3); }
        else if (slot < 40) { int s = slot - 32; kt = 9 + (s >> 1); nt = 2 + (s & 1); }
        else                { kt = 13 + (slot - 40); nt = 3; }
        int kbase = 32*kt + 8*(l >> 4);
        int m = 16 + 8 * (16*nt + (l & 15));   // m_d = 16+8d
        H8 bh;
        #pragma unroll
        for (int jj = 0; jj < 4; ++jj) {
            float v[2];
            #pragma unroll
            for (int h = 0; h < 2; ++h) {
                int k  = kbase + 2*jj + h;
                int ai = m - k;
                float s2 = 1.0f / (1.0f + __expf(-500.0f * tshs[k]));
                v[h] = (ai >= 0 && ai < 512) ? s2 * ws[WS_AIF + ai] * 0.125f : 0.0f;
            }
            bh.h2[jj] = (fp16x2){(__fp16)v[0], (__fp16)v[1]};   // RTN
        }
        Bs[idx] = bh.i4;
    }
    __syncthreads();

    // ---- hoist B into registers (iteration-invariant) ----
    i32x4 Breg[NSLOT];
    #pragma unroll
    for (int s = 0; s < NSLOT; ++s) Breg[s] = Bs[s*64 + lane];

    const int pixbase = blockIdx.x * 64 + wid * 16;
    const int mypix   = pixbase + n;

    float A  = eta[mypix];
    float K  = eta[NPIX + mypix];
    float T0 = eta[2*NPIX + mypix];
    const float pA = A, pK = K, pT = T0;

    // ctc_dc in C-layout registers: dcreg[nt][reg] = dc[p=q*4+reg][d=nt*16+n]
    float dcreg[4][4];
    #pragma unroll
    for (int reg = 0; reg < 4; ++reg) {
        const float* cp = ctc + (pixbase + q*4 + reg) * T_IN;
        float m5 = 0.2f * (cp[0]+cp[1]+cp[2]+cp[3]+cp[4]);
        #pragma unroll
        for (int nt = 0; nt < 4; ++nt) {
            int d = nt*16 + n;
            float cc = cp[d] - m5;
            float cm = cp[(d > 0) ? d-1 : 0] - m5;
            dcreg[nt][reg] = (d == 0) ? cc : (0.4375f*cm + 0.5625f*cc);
        }
    }

    const float C_dc = ws[WS_CDC];
    const float spl  = ws[WS_SPLAM];
    const float cdc2 = 2.0f / C_dc;
    const float rgA  = 2.0f * spl / ws[WS_CNN+0];
    const float rgK  = 2.0f * spl / ws[WS_CNN+1];
    const float rgT  = 2.0f * spl / ws[WS_CNN+2];

    constexpr int NTMIN[16] = {0,0,0,0,0,1,1,1,1,2,2,2,2,3,3,3};
    constexpr int TOFS[16]  = {0,4,8,12,16,20,23,26,29,32,34,36,38,40,41,42};

    #pragma unroll 1
    for (int it = 0; it < MAX_ITER; ++it) {
        f32x4 acc[3][4];
        #pragma unroll
        for (int f = 0; f < 3; ++f)
            #pragma unroll
            for (int t = 0; t < 4; ++t)
                acc[f][t] = (f32x4){0.f, 0.f, 0.f, 0.f};

        float nK = -K;
        float r  = __expf(0.125f * K);     // x ratio per t-step
        #pragma unroll
        for (int kt = 0; kt < 16; ++kt) {
            f32x4 tv0 = *(const f32x4*)&tshs[32*kt + 8*q];
            f32x4 tv1 = *(const f32x4*)&tshs[32*kt + 8*q + 4];
            float d1[8];
            d1[0]=T0-tv0[0]; d1[1]=T0-tv0[1]; d1[2]=T0-tv0[2]; d1[3]=T0-tv0[3];
            d1[4]=T0-tv1[0]; d1[5]=T0-tv1[1]; d1[6]=T0-tv1[2]; d1[7]=T0-tv1[3];
            float x[8];
            if (kt == 0 || kt == 15) {
                bool edge = (kt == 0) ? (q == 0) : (q == 3);  // flat tsh samples
                if (edge) {
                    #pragma unroll
                    for (int j = 0; j < 8; ++j) x[j] = __expf(nK * d1[j]);
                } else {
                    x[0] = __expf(nK * d1[0]);
                    #pragma unroll
                    for (int j = 1; j < 8; ++j) x[j] = x[j-1] * r;
                }
            } else {
                x[0] = __expf(nK * d1[0]);
                #pragma unroll
                for (int j = 1; j < 8; ++j) x[j] = x[j-1] * r;
            }
            H8 F0h, F1h, F2h;
            #pragma unroll
            for (int jj = 0; jj < 4; ++jj) {
                float s1a = rcp_fast(1.0f + x[2*jj]);
                float s1b = rcp_fast(1.0f + x[2*jj+1]);
                fp16x2 sh  = (fp16x2){(__fp16)s1a, (__fp16)s1b};          // RTN
                fp16x2 d1h = __builtin_amdgcn_cvt_pkrtz(d1[2*jj], d1[2*jj+1]);
                fp16x2 eh  = sh - sh*sh;                                  // v_pk f16
                F0h.h2[jj] = sh;
                F1h.h2[jj] = eh * d1h;
                F2h.h2[jj] = eh;
            }
            #pragma unroll
            for (int nt = NTMIN[kt]; nt < 4; ++nt) {
                int slot = TOFS[kt] + nt - NTMIN[kt];
                H8 bh; bh.i4 = Breg[slot];
                acc[0][nt] = __builtin_amdgcn_mfma_f32_16x16x32_f16(F0h.v, bh.v, acc[0][nt], 0, 0, 0);
                acc[1][nt] = __builtin_amdgcn_mfma_f32_16x16x32_f16(F1h.v, bh.v, acc[1][nt], 0, 0, 0);
                acc[2][nt] = __builtin_amdgcn_mfma_f32_16x16x32_f16(F2h.v, bh.v, acc[2][nt], 0, 0, 0);
            }
        }

        // ---- epilogue: residuals, per-pixel gradient dots, reduce, route ----
        float Ap[4];
        #pragma unroll
        for (int rr2 = 0; rr2 < 4; ++rr2) Ap[rr2] = __shfl(A, q*4 + rr2);

        float SA[4], SK[4], ST[4];
        #pragma unroll
        for (int r2 = 0; r2 < 4; ++r2) { SA[r2]=0.f; SK[r2]=0.f; ST[r2]=0.f; }
        #pragma unroll
        for (int nt = 0; nt < 4; ++nt)
            #pragma unroll
            for (int r2 = 0; r2 < 4; ++r2) {
                float Y0 = acc[0][nt][r2], Y1 = acc[1][nt][r2], Y2 = acc[2][nt][r2];
                float rr = fmaf(Ap[r2], Y0, -dcreg[nt][r2]);   // est - dc
                SA[r2] = fmaf(rr, Y0, SA[r2]);
                SK[r2] = fmaf(rr, Y1, SK[r2]);
                ST[r2] = fmaf(rr, Y2, ST[r2]);
            }
        #pragma unroll
        for (int r2 = 0; r2 < 4; ++r2)
            #pragma unroll
            for (int m = 1; m < 16; m <<= 1) {
                SA[r2] += __shfl_xor(SA[r2], m);
                SK[r2] += __shfl_xor(SK[r2], m);
                ST[r2] += __shfl_xor(ST[r2], m);
            }
        // route: pixel p=n lives in group p>>2, slot p&3
        int src = (n >> 2) * 16;
        float GA = 0.f, GK = 0.f, GT = 0.f;
        #pragma unroll
        for (int r2 = 0; r2 < 4; ++r2) {
            float tA = __shfl(SA[r2], src);
            float tK = __shfl(SK[r2], src);
            float tT = __shfl(ST[r2], src);
            if ((n & 3) == r2) { GA = tA; GK = tK; GT = tT; }
        }

        float gA = fmaf(rgA, A  - pA, cdc2 * GA)         + 2.0f * fminf(A,  0.f);
        float gK = fmaf(rgK, K  - pK, cdc2 * A * GK)     + 2.0f * fminf(K,  0.f);
        float gT = fmaf(rgT, T0 - pT, cdc2 * A * K * GT) + 2.0f * fminf(T0, 0.f);
        A  -= 0.1f * gA;
        K  -= 0.1f * gK;
        T0 -= 0.1f * gT;
    }

    if (lane < 16) {
        out[mypix]          = A;
        out[NPIX + mypix]   = K;
        out[2*NPIX + mypix] = T0;
    }
}

// -------------------------------------------------------------- launch ------
extern "C" void kernel_launch(void* const* d_in, const int* in_sizes, int n_in,
                              void* d_out, int out_size, void* d_ws, size_t ws_size,
                              hipStream_t stream) {
    const float* ctc   = (const float*)d_in[0];
    const float* aif   = (const float*)d_in[1];
    const float* timev = (const float*)d_in[2];
    const float* eta   = (const float*)d_in[4];
    const float* lam   = (const float*)d_in[5];
    float* ws  = (float*)d_ws;
    float* out = (float*)d_out;

    (void)hipMemsetAsync(ws, 0, 8 * sizeof(float), stream);
    k_prep<<<1073, 256, 0, stream>>>(aif, timev, lam, ctc, eta, ws);
    k_main<<<NPIX / 64, 256, 0, stream>>>(ctc, eta, ws, out);
}